// Round 7
// baseline (166.676 us; speedup 1.0000x reference)
//
#include <hip/hip_runtime.h>

#define IDIM   78464
#define XCOLS  78466   // IDIM + 2 (female, age)
#define PCD    1936
#define PCD2   1938
#define KK     9
#define CC     600
#define BB     256
#define CH     8                  // chunks per row-dot in k3
#define CHLEN  (IDIM / CH / 2)    // float2 per chunk = 4904
#define NBLK_B ((BB + 1) * CH)    // 2056

// k2 row partition: 640 blocks * 39 rows + 1408 blocks * 38 rows = 78464
#define NBLK_A   2048
#define NBLK_HI  640

typedef float f4 __attribute__((ext_vector_type(4)));
typedef float f2 __attribute__((ext_vector_type(2)));

// ws layout (float offsets):
//  [0 .. 1937]               v[1936], v[1937] live at 1936/1937 (rest unused)
//  [2048 .. 2048+NBLK_B-1]   partial row-dots [257][8] (row 256 = center)
//  [8192 .. 8192+IDIM-1]     u = R @ v
#define WS_V    0
#define WS_P    2048
#define WS_U    8192

// Fused v-build (per-block LDS scatter) + u[row] = dot(rot[row,:], v).
// Block-contiguous rows (R5's proven stream shape); per-thread v fragment
// in 8 VGPRs; NT loads on the rot stream; no per-row barrier; coalesced
// u store. Block 0 publishes v[1936..1937] for k4.
__global__ __launch_bounds__(256) void k2_matvec(const float* __restrict__ rot,
                                                 const int* __restrict__ feats,
                                                 const float* __restrict__ w1,
                                                 const float* __restrict__ w2,
                                                 float* __restrict__ u,
                                                 float* __restrict__ ws) {
    __shared__ __align__(16) float vl[2048];       // zero-padded past 1938
    __shared__ float part[40 * 4];
    const int tid  = threadIdx.x;
    const int wave = tid >> 6;
    const int lane = tid & 63;

    for (int i = tid; i < 2048; i += 256) vl[i] = 0.0f;
    __syncthreads();
    for (int t = tid; t < KK * CC; t += 256) {
        int k = t / CC;
        atomicAdd(&vl[feats[t]], w2[k] * w1[t]);
    }
    __syncthreads();

    if (blockIdx.x == 0 && tid < 2) ws[WS_V + PCD + tid] = vl[PCD + tid];

    const int b    = blockIdx.x;
    const int hi   = (b < NBLK_HI);
    const int row0 = hi ? b * 39 : NBLK_HI * 39 + (b - NBLK_HI) * 38;
    const int nrows = hi ? 39 : 38;

    // row-invariant per-thread v fragment (484 f4 per row; pass1 covers 256)
    const f4* v4 = reinterpret_cast<const f4*>(vl);
    f4 vr0 = v4[tid];
    f4 vr1 = (tid < 228) ? v4[256 + tid] : (f4)(0.0f);

    const f4* r4 = reinterpret_cast<const f4*>(rot + (size_t)row0 * PCD);
    for (int r = 0; r < nrows; ++r) {
        f4 a0 = __builtin_nontemporal_load(&r4[tid]);
        f4 acc = a0 * vr0;
        if (tid < 228) {
            f4 a1 = __builtin_nontemporal_load(&r4[256 + tid]);
            acc += a1 * vr1;
        }
        float s = (acc.x + acc.y) + (acc.z + acc.w);
        #pragma unroll
        for (int off = 32; off; off >>= 1) s += __shfl_down(s, off, 64);
        if (lane == 0) part[r * 4 + wave] = s;
        r4 += PCD / 4;   // next contiguous row
    }
    __syncthreads();
    if (tid < nrows)
        u[row0 + tid] = (part[tid * 4 + 0] + part[tid * 4 + 1])
                      + (part[tid * 4 + 2] + part[tid * 4 + 3]);
}

// partial[b][c] = dot(row_b[chunk c], u[chunk c]) ; row 256 = center
__global__ __launch_bounds__(256) void k3_partial(const float* __restrict__ x,
                                                  const float* __restrict__ center,
                                                  const float* __restrict__ u,
                                                  float* __restrict__ part) {
    __shared__ float wred[4];
    const int bid = blockIdx.x;
    const int b = bid >> 3;
    const int c = bid & (CH - 1);
    const float* row = (b < BB) ? (x + (size_t)b * XCOLS) : center;
    const f2* r2 = reinterpret_cast<const f2*>(row);
    const f2* u2 = reinterpret_cast<const f2*>(u);
    const int j0 = c * CHLEN;
    float ax = 0.f, ay = 0.f;
    for (int j = j0 + threadIdx.x; j < j0 + CHLEN; j += 256) {
        f2 a  = __builtin_nontemporal_load(&r2[j]);
        f2 uu = u2[j];
        ax += a.x * uu.x; ay += a.y * uu.y;
    }
    float s = ax + ay;
    #pragma unroll
    for (int off = 32; off; off >>= 1) s += __shfl_down(s, off, 64);
    const int wave = threadIdx.x >> 6;
    const int lane = threadIdx.x & 63;
    if (lane == 0) wred[wave] = s;
    __syncthreads();
    if (threadIdx.x == 0) part[bid] = (wred[0] + wred[1]) + (wred[2] + wred[3]);
}

// out[b] = rowsum_b - c.u + female*(v[1936]+w2[10]) + age*(v[1937]+w2[9]) + sum_k b1[k]*w2[k] + b2
__global__ __launch_bounds__(256) void k4_final(const float* __restrict__ x,
                                                const float* __restrict__ b1,
                                                const float* __restrict__ w2,
                                                const float* __restrict__ b2,
                                                const float* __restrict__ ws,
                                                float* __restrict__ out) {
    int b = threadIdx.x;
    if (b < BB) {
        float female = x[(size_t)b * XCOLS + IDIM];
        float age    = x[(size_t)b * XCOLS + IDIM + 1];
        float s = 0.f, cu = 0.f;
        #pragma unroll
        for (int c = 0; c < CH; ++c) {
            s  += ws[WS_P + b * CH + c];
            cu += ws[WS_P + BB * CH + c];
        }
        float cst = b2[0];
        #pragma unroll
        for (int k = 0; k < KK; ++k) cst += b1[k] * w2[k];
        out[b] = s - cu
               + female * (ws[WS_V + 1936] + w2[10])
               + age    * (ws[WS_V + 1937] + w2[9])
               + cst;
    }
}

extern "C" void kernel_launch(void* const* d_in, const int* in_sizes, int n_in,
                              void* d_out, int out_size, void* d_ws, size_t ws_size,
                              hipStream_t stream) {
    const float* x      = (const float*)d_in[0];
    const float* center = (const float*)d_in[1];
    const float* rot    = (const float*)d_in[2];
    const int*   feats  = (const int*)  d_in[3];
    const float* w1     = (const float*)d_in[4];
    const float* b1     = (const float*)d_in[5];
    const float* w2     = (const float*)d_in[6];
    const float* b2     = (const float*)d_in[7];
    float* ws  = (float*)d_ws;
    float* out = (float*)d_out;

    hipLaunchKernelGGL(k2_matvec, dim3(NBLK_A), dim3(256), 0, stream,
                       rot, feats, w1, w2, ws + WS_U, ws);
    hipLaunchKernelGGL(k3_partial, dim3(NBLK_B), dim3(256), 0, stream,
                       x, center, ws + WS_U, ws + WS_P);
    hipLaunchKernelGGL(k4_final,  dim3(1),      dim3(256),  0, stream,
                       x, b1, w2, b2, ws, out);
}

// Round 8
// 127.391 us; speedup vs baseline: 1.3084x; 1.3084x over previous
//
#include <hip/hip_runtime.h>

#define IDIM   78464
#define XCOLS  78466   // IDIM + 2 (female, age)
#define PCD    1936
#define PCD2   1938
#define KK     9
#define CC     600
#define BB     256
#define CH     8                  // chunks per row-dot in k3
#define CHLEN  (IDIM / CH / 2)    // float2 per chunk = 4904
#define NBLK_B ((BB + 1) * CH)    // 2056

// k2 row partition: 640 blocks * 39 rows + 1408 blocks * 38 rows = 78464
#define NBLK_A   2048
#define NBLK_HI  640

typedef float f4 __attribute__((ext_vector_type(4)));
typedef float f2 __attribute__((ext_vector_type(2)));

// ws layout (float offsets):
//  [0 .. 1937]               v  (scatter of w2[k]*w1[k,c] by feats)
//  [2048 .. 2048+NBLK_B-1]   partial row-dots [257][8] (row 256 = center)
//  [8192 .. 8192+IDIM-1]     u = R @ v
#define WS_V    0
#define WS_P    2048
#define WS_U    8192

// build v in LDS (zero + scatter via LDS atomics), write out. One block.
__global__ __launch_bounds__(1024) void k1_buildv(const int* __restrict__ feats,
                                                  const float* __restrict__ w1,
                                                  const float* __restrict__ w2,
                                                  float* __restrict__ ws) {
    __shared__ float vl[PCD2];
    for (int i = threadIdx.x; i < PCD2; i += 1024) vl[i] = 0.0f;
    __syncthreads();
    for (int t = threadIdx.x; t < KK * CC; t += 1024) {
        int k = t / CC;
        atomicAdd(&vl[feats[t]], w2[k] * w1[t]);
    }
    __syncthreads();
    for (int i = threadIdx.x; i < PCD2; i += 1024) ws[WS_V + i] = vl[i];
}

// u[row] = dot(rot[row,:], v) — block-chunked contiguous rows (proven stream
// shape). 256 threads sweep each row in 2 fixed passes; per-thread v fragment
// in 8 VGPRs; NT loads on the zero-reuse rot stream; no per-row barrier;
// coalesced u store.
__global__ __launch_bounds__(256) void k2_matvec(const float* __restrict__ rot,
                                                 const float* __restrict__ v_in,
                                                 float* __restrict__ u) {
    __shared__ float part[40 * 4];
    const int tid  = threadIdx.x;
    const int wave = tid >> 6;
    const int lane = tid & 63;
    const int b    = blockIdx.x;
    const int hi   = (b < NBLK_HI);
    const int row0 = hi ? b * 39 : NBLK_HI * 39 + (b - NBLK_HI) * 38;
    const int nrows = hi ? 39 : 38;

    // row-invariant per-thread v fragment (484 f4 per row; pass1 covers 256)
    const f4* v4 = reinterpret_cast<const f4*>(v_in);
    f4 vr0 = v4[tid];
    f4 vr1 = (tid < 228) ? v4[256 + tid] : (f4)(0.0f);

    const f4* r4 = reinterpret_cast<const f4*>(rot + (size_t)row0 * PCD);
    for (int r = 0; r < nrows; ++r) {
        f4 a0 = __builtin_nontemporal_load(&r4[tid]);
        f4 acc = a0 * vr0;
        if (tid < 228) {
            f4 a1 = __builtin_nontemporal_load(&r4[256 + tid]);
            acc += a1 * vr1;
        }
        float s = (acc.x + acc.y) + (acc.z + acc.w);
        #pragma unroll
        for (int off = 32; off; off >>= 1) s += __shfl_down(s, off, 64);
        if (lane == 0) part[r * 4 + wave] = s;
        r4 += PCD / 4;   // next contiguous row
    }
    __syncthreads();
    if (tid < nrows)
        u[row0 + tid] = (part[tid * 4 + 0] + part[tid * 4 + 1])
                      + (part[tid * 4 + 2] + part[tid * 4 + 3]);
}

// partial[b][c] = dot(row_b[chunk c], u[chunk c]) ; row 256 = center
__global__ __launch_bounds__(256) void k3_partial(const float* __restrict__ x,
                                                  const float* __restrict__ center,
                                                  const float* __restrict__ u,
                                                  float* __restrict__ part) {
    __shared__ float wred[4];
    const int bid = blockIdx.x;
    const int b = bid >> 3;
    const int c = bid & (CH - 1);
    const float* row = (b < BB) ? (x + (size_t)b * XCOLS) : center;
    const f2* r2 = reinterpret_cast<const f2*>(row);
    const f2* u2 = reinterpret_cast<const f2*>(u);
    const int j0 = c * CHLEN;
    float ax = 0.f, ay = 0.f;
    for (int j = j0 + threadIdx.x; j < j0 + CHLEN; j += 256) {
        f2 a  = __builtin_nontemporal_load(&r2[j]);
        f2 uu = u2[j];
        ax += a.x * uu.x; ay += a.y * uu.y;
    }
    float s = ax + ay;
    #pragma unroll
    for (int off = 32; off; off >>= 1) s += __shfl_down(s, off, 64);
    const int wave = threadIdx.x >> 6;
    const int lane = threadIdx.x & 63;
    if (lane == 0) wred[wave] = s;
    __syncthreads();
    if (threadIdx.x == 0) part[bid] = (wred[0] + wred[1]) + (wred[2] + wred[3]);
}

// out[b] = rowsum_b - c.u + female*(v[1936]+w2[10]) + age*(v[1937]+w2[9]) + sum_k b1[k]*w2[k] + b2
__global__ __launch_bounds__(256) void k4_final(const float* __restrict__ x,
                                                const float* __restrict__ b1,
                                                const float* __restrict__ w2,
                                                const float* __restrict__ b2,
                                                const float* __restrict__ ws,
                                                float* __restrict__ out) {
    int b = threadIdx.x;
    if (b < BB) {
        float female = x[(size_t)b * XCOLS + IDIM];
        float age    = x[(size_t)b * XCOLS + IDIM + 1];
        float s = 0.f, cu = 0.f;
        #pragma unroll
        for (int c = 0; c < CH; ++c) {
            s  += ws[WS_P + b * CH + c];
            cu += ws[WS_P + BB * CH + c];
        }
        float cst = b2[0];
        #pragma unroll
        for (int k = 0; k < KK; ++k) cst += b1[k] * w2[k];
        out[b] = s - cu
               + female * (ws[WS_V + 1936] + w2[10])
               + age    * (ws[WS_V + 1937] + w2[9])
               + cst;
    }
}

extern "C" void kernel_launch(void* const* d_in, const int* in_sizes, int n_in,
                              void* d_out, int out_size, void* d_ws, size_t ws_size,
                              hipStream_t stream) {
    const float* x      = (const float*)d_in[0];
    const float* center = (const float*)d_in[1];
    const float* rot    = (const float*)d_in[2];
    const int*   feats  = (const int*)  d_in[3];
    const float* w1     = (const float*)d_in[4];
    const float* b1     = (const float*)d_in[5];
    const float* w2     = (const float*)d_in[6];
    const float* b2     = (const float*)d_in[7];
    float* ws  = (float*)d_ws;
    float* out = (float*)d_out;

    hipLaunchKernelGGL(k1_buildv, dim3(1),      dim3(1024), 0, stream, feats, w1, w2, ws);
    hipLaunchKernelGGL(k2_matvec, dim3(NBLK_A), dim3(256),  0, stream, rot, ws + WS_V, ws + WS_U);
    hipLaunchKernelGGL(k3_partial, dim3(NBLK_B), dim3(256), 0, stream, x, center, ws + WS_U, ws + WS_P);
    hipLaunchKernelGGL(k4_final,  dim3(1),      dim3(256),  0, stream, x, b1, w2, b2, ws, out);
}